// Round 13
// baseline (279.814 us; speedup 1.0000x reference)
//
#include <hip/hip_runtime.h>
#include <hip/hip_fp16.h>
#include <math.h>

#define NEG_SLOPE 0.2f
#define LOG2E 1.44269504088896f

#if __has_builtin(__builtin_amdgcn_exp2f)
#define EXP2(x) __builtin_amdgcn_exp2f(x)
#else
#define EXP2(x) exp2f(x)
#endif

typedef _Float16 half8 __attribute__((ext_vector_type(8)));
typedef float floatx4 __attribute__((ext_vector_type(4)));

// ---------------- L1: pack W1 (blocks 0..15) + zero deg (blocks 16..) --------------
__global__ __launch_bounds__(256) void prep1(const float* __restrict__ W1,
                                             half8* __restrict__ Bpack,
                                             int* __restrict__ deg, int N) {
  if (blockIdx.x < 16) {
    int tid = blockIdx.x * 256 + threadIdx.x;  // 4096 total
    int l = tid & 63;
    int ksnt = tid >> 6;
    int ks = ksnt & 3;
    int nt = ksnt >> 2;
    int col = nt * 16 + (l & 15);
    int krow = ks * 32 + (l >> 4) * 8;
    half8 v;
#pragma unroll
    for (int j = 0; j < 8; j++) v[j] = (_Float16)W1[(krow + j) * 256 + col];
    Bpack[tid] = v;
  } else {
    int i = (blockIdx.x - 16) * 256 + threadIdx.x;
    if (i < N) deg[i] = 0;
  }
}

// ---------------- L2: gemm1 MFMA -> int8 h1 (per-row scale) + att dots ∥ hist+rank --
__global__ __launch_bounds__(256) void phase2(
    const float* __restrict__ x, const half8* __restrict__ Bpack,
    const float* __restrict__ att_s, const float* __restrict__ att_d,
    unsigned char* __restrict__ h1q, float* __restrict__ hscale,
    float* __restrict__ a1s, float* __restrict__ a1d,
    const int* __restrict__ dst, int* __restrict__ deg, int* __restrict__ rank,
    int N, int E, int gemmBlocks, int histBlocks) {
  if ((int)blockIdx.x >= gemmBlocks) {
    int b = blockIdx.x - gemmBlocks;
    for (int e = b * 256 + threadIdx.x; e < E; e += histBlocks * 256)
      rank[e] = atomicAdd(deg + dst[e], 1);
    return;
  }
  const int wave = threadIdx.x >> 6, lane = threadIdx.x & 63;
  const int quad = lane >> 4, li = lane & 15;
  const int n0 = (blockIdx.x * 4 + wave) * 16;
  if (n0 >= N) return;
  floatx4 acc[16];
#pragma unroll
  for (int t = 0; t < 16; t++) acc[t] = (floatx4){0.f, 0.f, 0.f, 0.f};
  const float* xrow = x + (size_t)(n0 + li) * 128;
#pragma unroll
  for (int ks = 0; ks < 4; ks++) {
    float4 xa = *(const float4*)(xrow + ks * 32 + quad * 8);
    float4 xb = *(const float4*)(xrow + ks * 32 + quad * 8 + 4);
    half8 a;
    a[0] = (_Float16)xa.x; a[1] = (_Float16)xa.y;
    a[2] = (_Float16)xa.z; a[3] = (_Float16)xa.w;
    a[4] = (_Float16)xb.x; a[5] = (_Float16)xb.y;
    a[6] = (_Float16)xb.z; a[7] = (_Float16)xb.w;
#pragma unroll
    for (int nt = 0; nt < 16; nt++) {
      half8 b = Bpack[(nt * 4 + ks) * 64 + lane];
      acc[nt] = __builtin_amdgcn_mfma_f32_16x16x32_f16(a, b, acc[nt], 0, 0, 0);
    }
  }
  // int8 quantize: row (m = quad*4 + r) absmax over 256 ch -> scale
#pragma unroll
  for (int r = 0; r < 4; r++) {
    float m = 0.f;
#pragma unroll
    for (int nt = 0; nt < 16; nt++) m = fmaxf(m, fabsf(acc[nt][r]));
#pragma unroll
    for (int off = 8; off > 0; off >>= 1) m = fmaxf(m, __shfl_xor(m, off, 16));
    m = fmaxf(m, 1e-8f);
    float inv = 127.0f / m;
    int node = n0 + quad * 4 + r;
    if (li == 0) hscale[node] = m * (1.0f / 127.0f);
#pragma unroll
    for (int nt = 0; nt < 16; nt++) {
      h1q[(size_t)node * 256 + nt * 16 + li] =
          (unsigned char)(int)(fmaf(acc[nt][r], inv, 128.5f));
    }
  }
  // fused attention dots (fp32 acc, pre-quantization), pre-scaled by log2e
  float as_f[16], ad_f[16];
#pragma unroll
  for (int nt = 0; nt < 16; nt++) {
    as_f[nt] = att_s[nt * 16 + li];
    ad_f[nt] = att_d[nt * 16 + li];
  }
#pragma unroll
  for (int r = 0; r < 4; r++) {
    int node = n0 + quad * 4 + r;
#pragma unroll
    for (int h = 0; h < 4; h++) {
      float vs = 0.f, vd = 0.f;
#pragma unroll
      for (int ntl = 0; ntl < 4; ntl++) {
        int nt = h * 4 + ntl;
        vs = fmaf(acc[nt][r], as_f[nt], vs);
        vd = fmaf(acc[nt][r], ad_f[nt], vd);
      }
#pragma unroll
      for (int off = 8; off > 0; off >>= 1) {
        vs += __shfl_down(vs, off, 16);
        vd += __shfl_down(vd, off, 16);
      }
      if (li == 0) {
        a1s[node * 4 + h] = vs * LOG2E;
        a1d[node * 4 + h] = vd * LOG2E;
      }
    }
  }
}

// ---------------- CSR scan chain (unpadded rows) ----------------
__global__ void scan_local(const int* __restrict__ deg, int* __restrict__ excl,
                           int* __restrict__ bsum, int N) {
  __shared__ int s[256];
  int i = blockIdx.x * 256 + threadIdx.x;
  int v = (i < N) ? deg[i] + 1 : 0;  // +1 self-loop
  s[threadIdx.x] = v;
  __syncthreads();
  for (int off = 1; off < 256; off <<= 1) {
    int t = (threadIdx.x >= off) ? s[threadIdx.x - off] : 0;
    __syncthreads();
    s[threadIdx.x] += t;
    __syncthreads();
  }
  if (i < N) excl[i] = s[threadIdx.x] - v;
  if (threadIdx.x == 255) bsum[blockIdx.x] = s[255];
}

// scan_add2: every block re-scans bsum in LDS (nb <= 256), writes rowptr + self-loop
__global__ void scan_add2(const int* __restrict__ excl, const int* __restrict__ bsum,
                          int* __restrict__ rowptr, int* __restrict__ elist,
                          int N, int nb) {
  __shared__ int s[256];
  int v = (threadIdx.x < nb) ? bsum[threadIdx.x] : 0;
  s[threadIdx.x] = v;
  __syncthreads();
  for (int off = 1; off < 256; off <<= 1) {
    int t = (threadIdx.x >= off) ? s[threadIdx.x - off] : 0;
    __syncthreads();
    s[threadIdx.x] += t;
    __syncthreads();
  }
  __syncthreads();
  int base = (blockIdx.x > 0) ? s[blockIdx.x - 1] : 0;  // exclusive block offset
  int i = blockIdx.x * 256 + threadIdx.x;
  if (i < N) {
    int r = excl[i] + base;
    rowptr[i] = r;
    elist[r] = i;  // self-loop first
  }
  if (blockIdx.x == 0 && threadIdx.x == 0) rowptr[N] = s[nb - 1];  // total = ET
}

// ---------------- atomic-free scatter via precomputed rank ----------------
__global__ void scatter2(const int* __restrict__ src, const int* __restrict__ dst,
                         const int* __restrict__ rank, const int* __restrict__ rowptr,
                         int* __restrict__ elist, int E) {
  int e = blockIdx.x * 256 + threadIdx.x;
  if (e >= E) return;
  elist[rowptr[dst[e]] + 1 + rank[e]] = src[e];
}

// ---------------- agg1: TWO waves per node (edge-split halves, LDS combine),
// int8 h1 gather + inline fast-exp softmax + bias1 + ELU + GEMM2 + att2 dots -------
__global__ __launch_bounds__(256) void agg1_fused(
    const int* __restrict__ rowptr, const int* __restrict__ elist,
    const unsigned char* __restrict__ h1q, const float* __restrict__ hscale,
    const float* __restrict__ a1s, const float* __restrict__ a1d,
    const float* __restrict__ b1, const float* __restrict__ W2,
    const float* __restrict__ as2, const float* __restrict__ ad2,
    __half* __restrict__ h2, float* __restrict__ a2s, float* __restrict__ a2d,
    int N) {
  __shared__ float w2s[64 * 41];  // lane-stride 41 -> conflict-free
  __shared__ float comb[2][64][6];
  const int t = threadIdx.x;
  for (int i = t; i < 2560; i += 256) {
    int ch = i / 10, jj = i - ch * 10;
    w2s[(ch >> 2) * 41 + (ch & 3) * 10 + jj] = W2[i];
  }
  __syncthreads();

  const int wave = t >> 6, lane = t & 63;
  const int nn = wave >> 1;   // node slot within block (0..1)
  const int half = wave & 1;  // which half of the edge list
  const int n = blockIdx.x * 2 + nn;
  const bool act = n < N;
  const int row = act ? rowptr[n] : 0;
  const int deg = act ? rowptr[n + 1] - row : 0;
  const int* el = elist + row;
  const int hidx = lane >> 4;
  const float adh = act ? a1d[n * 4 + hidx] : 0.f;  // pre-scaled by log2e

  const int jbeg = half ? (deg >> 1) : 0;
  const int jend = half ? deg : (deg >> 1);

  float den = 0.f, T = 0.f;
  float acc0 = 0.f, acc1 = 0.f, acc2 = 0.f, acc3 = 0.f;
  int j = jbeg;
  for (; j + 8 <= jend; j += 8) {
    int ss[8];
#pragma unroll
    for (int u = 0; u < 8; u++) ss[u] = el[j + u];
    float lv[8], sc[8];
    unsigned int qv[8];
#pragma unroll
    for (int u = 0; u < 8; u++) {
      lv[u] = a1s[ss[u] * 4 + hidx];
      sc[u] = hscale[ss[u]];
      qv[u] = *(const unsigned int*)(h1q + (size_t)ss[u] * 256 + lane * 4);
    }
#pragma unroll
    for (int u = 0; u < 8; u++) {
      float l = lv[u] + adh;
      float e = EXP2(fmaxf(l, NEG_SLOPE * l));
      den += e;
      float se = e * sc[u];
      T += se;
      acc0 = fmaf((float)(qv[u] & 0xffu), se, acc0);
      acc1 = fmaf((float)((qv[u] >> 8) & 0xffu), se, acc1);
      acc2 = fmaf((float)((qv[u] >> 16) & 0xffu), se, acc2);
      acc3 = fmaf((float)(qv[u] >> 24), se, acc3);
    }
  }
  for (; j + 4 <= jend; j += 4) {
    int ss[4];
#pragma unroll
    for (int u = 0; u < 4; u++) ss[u] = el[j + u];
    float lv[4], sc[4];
    unsigned int qv[4];
#pragma unroll
    for (int u = 0; u < 4; u++) {
      lv[u] = a1s[ss[u] * 4 + hidx];
      sc[u] = hscale[ss[u]];
      qv[u] = *(const unsigned int*)(h1q + (size_t)ss[u] * 256 + lane * 4);
    }
#pragma unroll
    for (int u = 0; u < 4; u++) {
      float l = lv[u] + adh;
      float e = EXP2(fmaxf(l, NEG_SLOPE * l));
      den += e;
      float se = e * sc[u];
      T += se;
      acc0 = fmaf((float)(qv[u] & 0xffu), se, acc0);
      acc1 = fmaf((float)((qv[u] >> 8) & 0xffu), se, acc1);
      acc2 = fmaf((float)((qv[u] >> 16) & 0xffu), se, acc2);
      acc3 = fmaf((float)(qv[u] >> 24), se, acc3);
    }
  }
  for (; j < jend; j++) {
    int s0 = el[j];
    float l0 = a1s[s0 * 4 + hidx] + adh;
    float sc0 = hscale[s0];
    unsigned int q0 = *(const unsigned int*)(h1q + (size_t)s0 * 256 + lane * 4);
    float e0 = EXP2(fmaxf(l0, NEG_SLOPE * l0));
    den += e0;
    float se = e0 * sc0;
    T += se;
    acc0 = fmaf((float)(q0 & 0xffu), se, acc0);
    acc1 = fmaf((float)((q0 >> 8) & 0xffu), se, acc1);
    acc2 = fmaf((float)((q0 >> 16) & 0xffu), se, acc2);
    acc3 = fmaf((float)(q0 >> 24), se, acc3);
  }

  // combine halves: half-1 wave publishes its partials, half-0 wave finishes
  if (half) {
    comb[nn][lane][0] = acc0;
    comb[nn][lane][1] = acc1;
    comb[nn][lane][2] = acc2;
    comb[nn][lane][3] = acc3;
    comb[nn][lane][4] = den;
    comb[nn][lane][5] = T;
  }
  __syncthreads();
  if (half || !act) return;
  acc0 += comb[nn][lane][0];
  acc1 += comb[nn][lane][1];
  acc2 += comb[nn][lane][2];
  acc3 += comb[nn][lane][3];
  den += comb[nn][lane][4];
  T += comb[nn][lane][5];

  // undo the +128 offset: sum(se*(q-128)) = sum(se*q) - 128*sum(se)
  float corr = 128.0f * T;
  acc0 -= corr; acc1 -= corr; acc2 -= corr; acc3 -= corr;

  float inv = 1.0f / den;
  float4 bb = *(const float4*)(b1 + lane * 4);
  float c0 = fmaf(acc0, inv, bb.x);
  float c1 = fmaf(acc1, inv, bb.y);
  float c2 = fmaf(acc2, inv, bb.z);
  float c3 = fmaf(acc3, inv, bb.w);
  c0 = c0 > 0.f ? c0 : expm1f(c0);
  c1 = c1 > 0.f ? c1 : expm1f(c1);
  c2 = c2 > 0.f ? c2 : expm1f(c2);
  c3 = c3 > 0.f ? c3 : expm1f(c3);
  const float* w0 = w2s + lane * 41;
  float p[10];
#pragma unroll
  for (int jj = 0; jj < 10; jj++)
    p[jj] = fmaf(c0, w0[jj], fmaf(c1, w0[10 + jj], fmaf(c2, w0[20 + jj], c3 * w0[30 + jj])));
#pragma unroll
  for (int jj = 0; jj < 10; jj++) {
#pragma unroll
    for (int off = 32; off > 0; off >>= 1) p[jj] += __shfl_down(p[jj], off, 64);
  }
  if (lane == 0) {
    float ds = 0.f, dd = 0.f;
#pragma unroll
    for (int jj = 0; jj < 10; jj++) {
      h2[(size_t)n * 16 + jj] = __float2half(p[jj]);
      ds = fmaf(p[jj], as2[jj], ds);
      dd = fmaf(p[jj], ad2[jj], dd);
    }
    a2s[n] = ds * LOG2E;
    a2d[n] = dd * LOG2E;
  }
}

// ---------------- agg2: wave-per-node layer-2 aggregate (R10 proven form) ----------
__global__ __launch_bounds__(256) void agg2_csr(
    const int* __restrict__ rowptr, const int* __restrict__ elist,
    const __half* __restrict__ h2, const float* __restrict__ a2s,
    const float* __restrict__ a2d, const float* __restrict__ b2,
    float* __restrict__ out, int N) {
  int wave = threadIdx.x >> 6, lane = threadIdx.x & 63;
  int n = blockIdx.x * 4 + wave;
  if (n >= N) return;
  int row = rowptr[n];
  int deg = rowptr[n + 1] - row;
  const int* el = elist + row;
  float ad = a2d[n];  // pre-scaled
  int g = lane / 10;  // 0..5 active, lanes 60-63 idle
  int c = lane - g * 10;
  float den = 0.f, acc = 0.f;
  if (g < 6) {
    int jj = g;
    for (; jj + 6 < deg; jj += 12) {
      int sA = el[jj], sB = el[jj + 6];
      float lA = a2s[sA] + ad;
      float lB = a2s[sB] + ad;
      __half hA = h2[(size_t)sA * 16 + c];
      __half hB = h2[(size_t)sB * 16 + c];
      float eA = EXP2(fmaxf(lA, NEG_SLOPE * lA));
      float eB = EXP2(fmaxf(lB, NEG_SLOPE * lB));
      den += eA + eB;
      acc = fmaf(eA, __half2float(hA), fmaf(eB, __half2float(hB), acc));
    }
    for (; jj < deg; jj += 6) {
      int s = el[jj];
      float l = a2s[s] + ad;
      float ev = EXP2(fmaxf(l, NEG_SLOPE * l));
      den += ev;
      acc = fmaf(ev, __half2float(h2[(size_t)s * 16 + c]), acc);
    }
  }
  acc += __shfl_down(acc, 30, 64);
  den += __shfl_down(den, 30, 64);
  acc += __shfl_down(acc, 10, 64) + __shfl_down(acc, 20, 64);
  den += __shfl_down(den, 10, 64) + __shfl_down(den, 20, 64);
  if (lane < 10) out[(size_t)n * 10 + lane] = acc / den + b2[lane];
}

extern "C" void kernel_launch(void* const* d_in, const int* in_sizes, int n_in,
                              void* d_out, int out_size, void* d_ws, size_t ws_size,
                              hipStream_t stream) {
  const float* x = (const float*)d_in[0];
  const int* ei = (const int*)d_in[1];
  const float* W1 = (const float*)d_in[2];
  const float* as1 = (const float*)d_in[3];
  const float* ad1 = (const float*)d_in[4];
  const float* b1 = (const float*)d_in[5];
  const float* W2 = (const float*)d_in[6];
  const float* as2 = (const float*)d_in[7];
  const float* ad2 = (const float*)d_in[8];
  const float* b2 = (const float*)d_in[9];
  float* out = (float*)d_out;

  const int N = in_sizes[0] / 128;   // 50000
  const int E = in_sizes[1] / 2;     // 800000
  const int* srcp = ei;
  const int* dstp = ei + E;

  char* ws = (char*)d_ws;
  size_t off = 0;
  auto alloc = [&](size_t nbytes) {
    char* p = ws + off;
    off += (nbytes + 255) & ~(size_t)255;
    return p;
  };
  unsigned char* h1q = (unsigned char*)alloc((size_t)N * 256);
  float* hscale = (float*)alloc((size_t)N * 4);
  half8* Bpack = (half8*)alloc((size_t)4096 * 16);
  float* a1s = (float*)alloc((size_t)N * 4 * 4);
  float* a1d = (float*)alloc((size_t)N * 4 * 4);
  __half* h2 = (__half*)alloc((size_t)N * 16 * 2);
  float* a2sv = (float*)alloc((size_t)N * 4);
  float* a2dv = (float*)alloc((size_t)N * 4);
  int* deg = (int*)alloc((size_t)N * 4);
  int* excl = (int*)alloc((size_t)N * 4);
  int* bsum = (int*)alloc(256 * 4);
  int* rowptr = (int*)alloc((size_t)(N + 1) * 4);
  int* rank = (int*)alloc((size_t)E * 4);
  int* elist = (int*)alloc((size_t)(E + (size_t)N) * 4);

  const int nb = (N + 255) / 256;          // 196
  const int gemmBlocks = (N / 16 + 3) / 4; // 782
  const int histBlocks = 512;

  // L1: pack W1 + zero deg
  prep1<<<16 + nb, 256, 0, stream>>>(W1, Bpack, deg, N);
  // L2: gemm1 (MFMA -> int8 + scales, fused att dots) || hist+rank
  phase2<<<gemmBlocks + histBlocks, 256, 0, stream>>>(
      x, Bpack, as1, ad1, h1q, hscale, a1s, a1d, dstp, deg, rank, N, E,
      gemmBlocks, histBlocks);
  // CSR: scan, rowptr + self-loops, atomic-free scatter
  scan_local<<<nb, 256, 0, stream>>>(deg, excl, bsum, N);
  scan_add2<<<nb, 256, 0, stream>>>(excl, bsum, rowptr, elist, N, nb);
  scatter2<<<(E + 255) / 256, 256, 0, stream>>>(srcp, dstp, rank, rowptr, elist, E);
  // layer 1 aggregate (+ fused GEMM2 / att2): 2 waves per node
  agg1_fused<<<(N + 1) / 2, 256, 0, stream>>>(rowptr, elist, h1q, hscale, a1s, a1d,
                                              b1, W2, as2, ad2, h2, a2sv, a2dv, N);
  // layer 2 aggregate
  agg2_csr<<<(N + 3) / 4, 256, 0, stream>>>(rowptr, elist, h2, a2sv, a2dv, b2, out, N);
}

// Round 14
// 256.372 us; speedup vs baseline: 1.0914x; 1.0914x over previous
//
#include <hip/hip_runtime.h>
#include <hip/hip_fp16.h>
#include <math.h>

#define NEG_SLOPE 0.2f
#define LOG2E 1.44269504088896f

#if __has_builtin(__builtin_amdgcn_exp2f)
#define EXP2(x) __builtin_amdgcn_exp2f(x)
#else
#define EXP2(x) exp2f(x)
#endif

typedef _Float16 half8 __attribute__((ext_vector_type(8)));
typedef float floatx4 __attribute__((ext_vector_type(4)));

// ---------------- L1: pack W1 (blocks 0..15) + zero deg (blocks 16..) --------------
__global__ __launch_bounds__(256) void prep1(const float* __restrict__ W1,
                                             half8* __restrict__ Bpack,
                                             int* __restrict__ deg, int N) {
  if (blockIdx.x < 16) {
    int tid = blockIdx.x * 256 + threadIdx.x;  // 4096 total
    int l = tid & 63;
    int ksnt = tid >> 6;
    int ks = ksnt & 3;
    int nt = ksnt >> 2;
    int col = nt * 16 + (l & 15);
    int krow = ks * 32 + (l >> 4) * 8;
    half8 v;
#pragma unroll
    for (int j = 0; j < 8; j++) v[j] = (_Float16)W1[(krow + j) * 256 + col];
    Bpack[tid] = v;
  } else {
    int i = (blockIdx.x - 16) * 256 + threadIdx.x;
    if (i < N) deg[i] = 0;
  }
}

// ---------------- L2: gemm1 MFMA -> int8 h1 (per-row scale) + att dots ∥ hist+rank --
__global__ __launch_bounds__(256) void phase2(
    const float* __restrict__ x, const half8* __restrict__ Bpack,
    const float* __restrict__ att_s, const float* __restrict__ att_d,
    unsigned char* __restrict__ h1q, float* __restrict__ hscale,
    float* __restrict__ a1s, float* __restrict__ a1d,
    const int* __restrict__ dst, int* __restrict__ deg, int* __restrict__ rank,
    int N, int E, int gemmBlocks, int histBlocks) {
  if ((int)blockIdx.x >= gemmBlocks) {
    int b = blockIdx.x - gemmBlocks;
    for (int e = b * 256 + threadIdx.x; e < E; e += histBlocks * 256)
      rank[e] = atomicAdd(deg + dst[e], 1);
    return;
  }
  const int wave = threadIdx.x >> 6, lane = threadIdx.x & 63;
  const int quad = lane >> 4, li = lane & 15;
  const int n0 = (blockIdx.x * 4 + wave) * 16;
  if (n0 >= N) return;
  floatx4 acc[16];
#pragma unroll
  for (int t = 0; t < 16; t++) acc[t] = (floatx4){0.f, 0.f, 0.f, 0.f};
  const float* xrow = x + (size_t)(n0 + li) * 128;
#pragma unroll
  for (int ks = 0; ks < 4; ks++) {
    float4 xa = *(const float4*)(xrow + ks * 32 + quad * 8);
    float4 xb = *(const float4*)(xrow + ks * 32 + quad * 8 + 4);
    half8 a;
    a[0] = (_Float16)xa.x; a[1] = (_Float16)xa.y;
    a[2] = (_Float16)xa.z; a[3] = (_Float16)xa.w;
    a[4] = (_Float16)xb.x; a[5] = (_Float16)xb.y;
    a[6] = (_Float16)xb.z; a[7] = (_Float16)xb.w;
#pragma unroll
    for (int nt = 0; nt < 16; nt++) {
      half8 b = Bpack[(nt * 4 + ks) * 64 + lane];
      acc[nt] = __builtin_amdgcn_mfma_f32_16x16x32_f16(a, b, acc[nt], 0, 0, 0);
    }
  }
  // int8 quantize: row (m = quad*4 + r) absmax over 256 ch -> scale
#pragma unroll
  for (int r = 0; r < 4; r++) {
    float m = 0.f;
#pragma unroll
    for (int nt = 0; nt < 16; nt++) m = fmaxf(m, fabsf(acc[nt][r]));
#pragma unroll
    for (int off = 8; off > 0; off >>= 1) m = fmaxf(m, __shfl_xor(m, off, 16));
    m = fmaxf(m, 1e-8f);
    float inv = 127.0f / m;
    int node = n0 + quad * 4 + r;
    if (li == 0) hscale[node] = m * (1.0f / 127.0f);
#pragma unroll
    for (int nt = 0; nt < 16; nt++) {
      h1q[(size_t)node * 256 + nt * 16 + li] =
          (unsigned char)(int)(fmaf(acc[nt][r], inv, 128.5f));
    }
  }
  // fused attention dots (fp32 acc, pre-quantization), pre-scaled by log2e
  float as_f[16], ad_f[16];
#pragma unroll
  for (int nt = 0; nt < 16; nt++) {
    as_f[nt] = att_s[nt * 16 + li];
    ad_f[nt] = att_d[nt * 16 + li];
  }
#pragma unroll
  for (int r = 0; r < 4; r++) {
    int node = n0 + quad * 4 + r;
#pragma unroll
    for (int h = 0; h < 4; h++) {
      float vs = 0.f, vd = 0.f;
#pragma unroll
      for (int ntl = 0; ntl < 4; ntl++) {
        int nt = h * 4 + ntl;
        vs = fmaf(acc[nt][r], as_f[nt], vs);
        vd = fmaf(acc[nt][r], ad_f[nt], vd);
      }
#pragma unroll
      for (int off = 8; off > 0; off >>= 1) {
        vs += __shfl_down(vs, off, 16);
        vd += __shfl_down(vd, off, 16);
      }
      if (li == 0) {
        a1s[node * 4 + h] = vs * LOG2E;
        a1d[node * 4 + h] = vd * LOG2E;
      }
    }
  }
}

// ---------------- CSR scan chain (unpadded rows) ----------------
__global__ void scan_local(const int* __restrict__ deg, int* __restrict__ excl,
                           int* __restrict__ bsum, int N) {
  __shared__ int s[256];
  int i = blockIdx.x * 256 + threadIdx.x;
  int v = (i < N) ? deg[i] + 1 : 0;  // +1 self-loop
  s[threadIdx.x] = v;
  __syncthreads();
  for (int off = 1; off < 256; off <<= 1) {
    int t = (threadIdx.x >= off) ? s[threadIdx.x - off] : 0;
    __syncthreads();
    s[threadIdx.x] += t;
    __syncthreads();
  }
  if (i < N) excl[i] = s[threadIdx.x] - v;
  if (threadIdx.x == 255) bsum[blockIdx.x] = s[255];
}

// scan_add2: every block re-scans bsum in LDS (nb <= 256), writes rowptr + self-loop
__global__ void scan_add2(const int* __restrict__ excl, const int* __restrict__ bsum,
                          int* __restrict__ rowptr, int* __restrict__ elist,
                          int N, int nb) {
  __shared__ int s[256];
  int v = (threadIdx.x < nb) ? bsum[threadIdx.x] : 0;
  s[threadIdx.x] = v;
  __syncthreads();
  for (int off = 1; off < 256; off <<= 1) {
    int t = (threadIdx.x >= off) ? s[threadIdx.x - off] : 0;
    __syncthreads();
    s[threadIdx.x] += t;
    __syncthreads();
  }
  __syncthreads();
  int base = (blockIdx.x > 0) ? s[blockIdx.x - 1] : 0;  // exclusive block offset
  int i = blockIdx.x * 256 + threadIdx.x;
  if (i < N) {
    int r = excl[i] + base;
    rowptr[i] = r;
    elist[r] = i;  // self-loop first
  }
  if (blockIdx.x == 0 && threadIdx.x == 0) rowptr[N] = s[nb - 1];  // total = ET
}

// ---------------- atomic-free scatter via precomputed rank ----------------
__global__ void scatter2(const int* __restrict__ src, const int* __restrict__ dst,
                         const int* __restrict__ rank, const int* __restrict__ rowptr,
                         int* __restrict__ elist, int E) {
  int e = blockIdx.x * 256 + threadIdx.x;
  if (e >= E) return;
  elist[rowptr[dst[e]] + 1 + rank[e]] = src[e];
}

// ---------------- agg1: TWO nodes per wave (half-wave = one full node, 32 lanes x
// 8 int8 channels). One VMEM inst fetches 2 edges' rows. Epilogue staged through
// LDS cbuf, then the proven R10 epilogue (4ch/lane, stride-41 w2s) per node. --------
__global__ __launch_bounds__(256) void agg1_fused(
    const int* __restrict__ rowptr, const int* __restrict__ elist,
    const unsigned char* __restrict__ h1q, const float* __restrict__ hscale,
    const float* __restrict__ a1s, const float* __restrict__ a1d,
    const float* __restrict__ b1, const float* __restrict__ W2,
    const float* __restrict__ as2, const float* __restrict__ ad2,
    __half* __restrict__ h2, float* __restrict__ a2s, float* __restrict__ a2d,
    int N) {
  __shared__ float w2s[64 * 41];   // lane-stride 41 -> conflict-free
  __shared__ float cbuf[8][256];   // normalized pre-bias outputs of this block's nodes
  const int t = threadIdx.x;
  for (int i = t; i < 2560; i += 256) {
    int ch = i / 10, jj = i - ch * 10;
    w2s[(ch >> 2) * 41 + (ch & 3) * 10 + jj] = W2[i];
  }

  const int wave = t >> 6, lane = t & 63;
  const int half = lane >> 5, l32 = lane & 31;
  const int slot = wave * 2 + half;        // node slot in block: 0..7
  const int n = blockIdx.x * 8 + slot;
  const bool act = n < N;
  const int row = act ? rowptr[n] : 0;
  const int deg = act ? rowptr[n + 1] - row : 0;
  const int* el = elist + row;
  const int hidx = l32 >> 3;               // head of this lane's 8 channels
  const float adh = act ? a1d[n * 4 + hidx] : 0.f;  // pre-scaled by log2e

  float den = 0.f, T = 0.f;
  float acc[8];
#pragma unroll
  for (int k = 0; k < 8; k++) acc[k] = 0.f;

  int j = 0;
  for (; j + 4 <= deg; j += 4) {
    int ss[4];
    float lv[4], sc[4];
    uint2 qv[4];
#pragma unroll
    for (int u = 0; u < 4; u++) ss[u] = el[j + u];
#pragma unroll
    for (int u = 0; u < 4; u++) {
      lv[u] = a1s[ss[u] * 4 + hidx];
      sc[u] = hscale[ss[u]];
      qv[u] = *(const uint2*)(h1q + (size_t)ss[u] * 256 + l32 * 8);
    }
#pragma unroll
    for (int u = 0; u < 4; u++) {
      float l = lv[u] + adh;
      float e = EXP2(fmaxf(l, NEG_SLOPE * l));
      den += e;
      float se = e * sc[u];
      T += se;
      unsigned int a = qv[u].x, b = qv[u].y;
      acc[0] = fmaf((float)(a & 0xffu), se, acc[0]);
      acc[1] = fmaf((float)((a >> 8) & 0xffu), se, acc[1]);
      acc[2] = fmaf((float)((a >> 16) & 0xffu), se, acc[2]);
      acc[3] = fmaf((float)(a >> 24), se, acc[3]);
      acc[4] = fmaf((float)(b & 0xffu), se, acc[4]);
      acc[5] = fmaf((float)((b >> 8) & 0xffu), se, acc[5]);
      acc[6] = fmaf((float)((b >> 16) & 0xffu), se, acc[6]);
      acc[7] = fmaf((float)(b >> 24), se, acc[7]);
    }
  }
  for (; j < deg; j++) {
    int s0 = el[j];
    float l0 = a1s[s0 * 4 + hidx] + adh;
    float sc0 = hscale[s0];
    uint2 q0 = *(const uint2*)(h1q + (size_t)s0 * 256 + l32 * 8);
    float e0 = EXP2(fmaxf(l0, NEG_SLOPE * l0));
    den += e0;
    float se = e0 * sc0;
    T += se;
    unsigned int a = q0.x, b = q0.y;
    acc[0] = fmaf((float)(a & 0xffu), se, acc[0]);
    acc[1] = fmaf((float)((a >> 8) & 0xffu), se, acc[1]);
    acc[2] = fmaf((float)((a >> 16) & 0xffu), se, acc[2]);
    acc[3] = fmaf((float)(a >> 24), se, acc[3]);
    acc[4] = fmaf((float)(b & 0xffu), se, acc[4]);
    acc[5] = fmaf((float)((b >> 8) & 0xffu), se, acc[5]);
    acc[6] = fmaf((float)((b >> 16) & 0xffu), se, acc[6]);
    acc[7] = fmaf((float)(b >> 24), se, acc[7]);
  }

  // normalized, offset-corrected, pre-bias values -> LDS
  if (act) {
    float inv = 1.0f / den;
    float corr = 128.0f * T;
    float4 v0 = make_float4((acc[0] - corr) * inv, (acc[1] - corr) * inv,
                            (acc[2] - corr) * inv, (acc[3] - corr) * inv);
    float4 v1 = make_float4((acc[4] - corr) * inv, (acc[5] - corr) * inv,
                            (acc[6] - corr) * inv, (acc[7] - corr) * inv);
    *(float4*)&cbuf[slot][l32 * 8] = v0;
    *(float4*)&cbuf[slot][l32 * 8 + 4] = v1;
  }
  __syncthreads();

  // epilogue (R10 layout): wave handles its 2 nodes sequentially, 4 ch/lane
  float4 bb = *(const float4*)(b1 + lane * 4);
  const float* w0 = w2s + lane * 41;
#pragma unroll
  for (int pp = 0; pp < 2; pp++) {
    int slot2 = wave * 2 + pp;
    int n2 = blockIdx.x * 8 + slot2;
    if (n2 >= N) continue;  // uniform per wave
    float4 cv = *(const float4*)&cbuf[slot2][lane * 4];
    float c0 = cv.x + bb.x;
    float c1 = cv.y + bb.y;
    float c2 = cv.z + bb.z;
    float c3 = cv.w + bb.w;
    c0 = c0 > 0.f ? c0 : expm1f(c0);
    c1 = c1 > 0.f ? c1 : expm1f(c1);
    c2 = c2 > 0.f ? c2 : expm1f(c2);
    c3 = c3 > 0.f ? c3 : expm1f(c3);
    float p[10];
#pragma unroll
    for (int jj = 0; jj < 10; jj++)
      p[jj] = fmaf(c0, w0[jj],
              fmaf(c1, w0[10 + jj], fmaf(c2, w0[20 + jj], c3 * w0[30 + jj])));
#pragma unroll
    for (int jj = 0; jj < 10; jj++) {
#pragma unroll
      for (int off = 32; off > 0; off >>= 1) p[jj] += __shfl_down(p[jj], off, 64);
    }
    if (lane == 0) {
      float ds = 0.f, dd = 0.f;
#pragma unroll
      for (int jj = 0; jj < 10; jj++) {
        h2[(size_t)n2 * 16 + jj] = __float2half(p[jj]);
        ds = fmaf(p[jj], as2[jj], ds);
        dd = fmaf(p[jj], ad2[jj], dd);
      }
      a2s[n2] = ds * LOG2E;
      a2d[n2] = dd * LOG2E;
    }
  }
}

// ---------------- agg2: wave-per-node layer-2 aggregate (R10 proven form) ----------
__global__ __launch_bounds__(256) void agg2_csr(
    const int* __restrict__ rowptr, const int* __restrict__ elist,
    const __half* __restrict__ h2, const float* __restrict__ a2s,
    const float* __restrict__ a2d, const float* __restrict__ b2,
    float* __restrict__ out, int N) {
  int wave = threadIdx.x >> 6, lane = threadIdx.x & 63;
  int n = blockIdx.x * 4 + wave;
  if (n >= N) return;
  int row = rowptr[n];
  int deg = rowptr[n + 1] - row;
  const int* el = elist + row;
  float ad = a2d[n];  // pre-scaled
  int g = lane / 10;  // 0..5 active, lanes 60-63 idle
  int c = lane - g * 10;
  float den = 0.f, acc = 0.f;
  if (g < 6) {
    int jj = g;
    for (; jj + 6 < deg; jj += 12) {
      int sA = el[jj], sB = el[jj + 6];
      float lA = a2s[sA] + ad;
      float lB = a2s[sB] + ad;
      __half hA = h2[(size_t)sA * 16 + c];
      __half hB = h2[(size_t)sB * 16 + c];
      float eA = EXP2(fmaxf(lA, NEG_SLOPE * lA));
      float eB = EXP2(fmaxf(lB, NEG_SLOPE * lB));
      den += eA + eB;
      acc = fmaf(eA, __half2float(hA), fmaf(eB, __half2float(hB), acc));
    }
    for (; jj < deg; jj += 6) {
      int s = el[jj];
      float l = a2s[s] + ad;
      float ev = EXP2(fmaxf(l, NEG_SLOPE * l));
      den += ev;
      acc = fmaf(ev, __half2float(h2[(size_t)s * 16 + c]), acc);
    }
  }
  acc += __shfl_down(acc, 30, 64);
  den += __shfl_down(den, 30, 64);
  acc += __shfl_down(acc, 10, 64) + __shfl_down(acc, 20, 64);
  den += __shfl_down(den, 10, 64) + __shfl_down(den, 20, 64);
  if (lane < 10) out[(size_t)n * 10 + lane] = acc / den + b2[lane];
}

extern "C" void kernel_launch(void* const* d_in, const int* in_sizes, int n_in,
                              void* d_out, int out_size, void* d_ws, size_t ws_size,
                              hipStream_t stream) {
  const float* x = (const float*)d_in[0];
  const int* ei = (const int*)d_in[1];
  const float* W1 = (const float*)d_in[2];
  const float* as1 = (const float*)d_in[3];
  const float* ad1 = (const float*)d_in[4];
  const float* b1 = (const float*)d_in[5];
  const float* W2 = (const float*)d_in[6];
  const float* as2 = (const float*)d_in[7];
  const float* ad2 = (const float*)d_in[8];
  const float* b2 = (const float*)d_in[9];
  float* out = (float*)d_out;

  const int N = in_sizes[0] / 128;   // 50000
  const int E = in_sizes[1] / 2;     // 800000
  const int* srcp = ei;
  const int* dstp = ei + E;

  char* ws = (char*)d_ws;
  size_t off = 0;
  auto alloc = [&](size_t nbytes) {
    char* p = ws + off;
    off += (nbytes + 255) & ~(size_t)255;
    return p;
  };
  unsigned char* h1q = (unsigned char*)alloc((size_t)N * 256);
  float* hscale = (float*)alloc((size_t)N * 4);
  half8* Bpack = (half8*)alloc((size_t)4096 * 16);
  float* a1s = (float*)alloc((size_t)N * 4 * 4);
  float* a1d = (float*)alloc((size_t)N * 4 * 4);
  __half* h2 = (__half*)alloc((size_t)N * 16 * 2);
  float* a2sv = (float*)alloc((size_t)N * 4);
  float* a2dv = (float*)alloc((size_t)N * 4);
  int* deg = (int*)alloc((size_t)N * 4);
  int* excl = (int*)alloc((size_t)N * 4);
  int* bsum = (int*)alloc(256 * 4);
  int* rowptr = (int*)alloc((size_t)(N + 1) * 4);
  int* rank = (int*)alloc((size_t)E * 4);
  int* elist = (int*)alloc((size_t)(E + (size_t)N) * 4);

  const int nb = (N + 255) / 256;          // 196
  const int gemmBlocks = (N / 16 + 3) / 4; // 782
  const int histBlocks = 512;

  // L1: pack W1 + zero deg
  prep1<<<16 + nb, 256, 0, stream>>>(W1, Bpack, deg, N);
  // L2: gemm1 (MFMA -> int8 + scales, fused att dots) || hist+rank
  phase2<<<gemmBlocks + histBlocks, 256, 0, stream>>>(
      x, Bpack, as1, ad1, h1q, hscale, a1s, a1d, dstp, deg, rank, N, E,
      gemmBlocks, histBlocks);
  // CSR: scan, rowptr + self-loops, atomic-free scatter
  scan_local<<<nb, 256, 0, stream>>>(deg, excl, bsum, N);
  scan_add2<<<nb, 256, 0, stream>>>(excl, bsum, rowptr, elist, N, nb);
  scatter2<<<(E + 255) / 256, 256, 0, stream>>>(srcp, dstp, rank, rowptr, elist, E);
  // layer 1 aggregate (+ fused GEMM2 / att2): 2 nodes per wave, 8 per block
  agg1_fused<<<(N + 7) / 8, 256, 0, stream>>>(rowptr, elist, h1q, hscale, a1s, a1d,
                                              b1, W2, as2, ad2, h2, a2sv, a2dv, N);
  // layer 2 aggregate
  agg2_csr<<<(N + 3) / 4, 256, 0, stream>>>(rowptr, elist, h2, a2sv, a2dv, b2, out, N);
}

// Round 15
// 256.080 us; speedup vs baseline: 1.0927x; 1.0011x over previous
//
#include <hip/hip_runtime.h>
#include <hip/hip_fp16.h>
#include <math.h>

#define NEG_SLOPE 0.2f
#define LOG2E 1.44269504088896f

#if __has_builtin(__builtin_amdgcn_exp2f)
#define EXP2(x) __builtin_amdgcn_exp2f(x)
#else
#define EXP2(x) exp2f(x)
#endif

typedef _Float16 half8 __attribute__((ext_vector_type(8)));
typedef float floatx4 __attribute__((ext_vector_type(4)));

// ---------------- L1: pack W1 (blocks 0..15) + zero deg (blocks 16..) --------------
__global__ __launch_bounds__(256) void prep1(const float* __restrict__ W1,
                                             half8* __restrict__ Bpack,
                                             int* __restrict__ deg, int N) {
  if (blockIdx.x < 16) {
    int tid = blockIdx.x * 256 + threadIdx.x;  // 4096 total
    int l = tid & 63;
    int ksnt = tid >> 6;
    int ks = ksnt & 3;
    int nt = ksnt >> 2;
    int col = nt * 16 + (l & 15);
    int krow = ks * 32 + (l >> 4) * 8;
    half8 v;
#pragma unroll
    for (int j = 0; j < 8; j++) v[j] = (_Float16)W1[(krow + j) * 256 + col];
    Bpack[tid] = v;
  } else {
    int i = (blockIdx.x - 16) * 256 + threadIdx.x;
    if (i < N) deg[i] = 0;
  }
}

// ---------------- L2: gemm1 MFMA -> int8 h1 (per-row scale) + att dots ∥ hist+rank --
__global__ __launch_bounds__(256) void phase2(
    const float* __restrict__ x, const half8* __restrict__ Bpack,
    const float* __restrict__ att_s, const float* __restrict__ att_d,
    unsigned char* __restrict__ h1q, float* __restrict__ hscale,
    float* __restrict__ a1s, float* __restrict__ a1d,
    const int* __restrict__ dst, int* __restrict__ deg, int* __restrict__ rank,
    int N, int E, int gemmBlocks, int histBlocks) {
  if ((int)blockIdx.x >= gemmBlocks) {
    int b = blockIdx.x - gemmBlocks;
    for (int e = b * 256 + threadIdx.x; e < E; e += histBlocks * 256)
      rank[e] = atomicAdd(deg + dst[e], 1);
    return;
  }
  const int wave = threadIdx.x >> 6, lane = threadIdx.x & 63;
  const int quad = lane >> 4, li = lane & 15;
  const int n0 = (blockIdx.x * 4 + wave) * 16;
  if (n0 >= N) return;
  floatx4 acc[16];
#pragma unroll
  for (int t = 0; t < 16; t++) acc[t] = (floatx4){0.f, 0.f, 0.f, 0.f};
  const float* xrow = x + (size_t)(n0 + li) * 128;
#pragma unroll
  for (int ks = 0; ks < 4; ks++) {
    float4 xa = *(const float4*)(xrow + ks * 32 + quad * 8);
    float4 xb = *(const float4*)(xrow + ks * 32 + quad * 8 + 4);
    half8 a;
    a[0] = (_Float16)xa.x; a[1] = (_Float16)xa.y;
    a[2] = (_Float16)xa.z; a[3] = (_Float16)xa.w;
    a[4] = (_Float16)xb.x; a[5] = (_Float16)xb.y;
    a[6] = (_Float16)xb.z; a[7] = (_Float16)xb.w;
#pragma unroll
    for (int nt = 0; nt < 16; nt++) {
      half8 b = Bpack[(nt * 4 + ks) * 64 + lane];
      acc[nt] = __builtin_amdgcn_mfma_f32_16x16x32_f16(a, b, acc[nt], 0, 0, 0);
    }
  }
  // int8 quantize: row (m = quad*4 + r) absmax over 256 ch -> scale
#pragma unroll
  for (int r = 0; r < 4; r++) {
    float m = 0.f;
#pragma unroll
    for (int nt = 0; nt < 16; nt++) m = fmaxf(m, fabsf(acc[nt][r]));
#pragma unroll
    for (int off = 8; off > 0; off >>= 1) m = fmaxf(m, __shfl_xor(m, off, 16));
    m = fmaxf(m, 1e-8f);
    float inv = 127.0f / m;
    int node = n0 + quad * 4 + r;
    if (li == 0) hscale[node] = m * (1.0f / 127.0f);
#pragma unroll
    for (int nt = 0; nt < 16; nt++) {
      h1q[(size_t)node * 256 + nt * 16 + li] =
          (unsigned char)(int)(fmaf(acc[nt][r], inv, 128.5f));
    }
  }
  // fused attention dots (fp32 acc, pre-quantization), pre-scaled by log2e
  float as_f[16], ad_f[16];
#pragma unroll
  for (int nt = 0; nt < 16; nt++) {
    as_f[nt] = att_s[nt * 16 + li];
    ad_f[nt] = att_d[nt * 16 + li];
  }
#pragma unroll
  for (int r = 0; r < 4; r++) {
    int node = n0 + quad * 4 + r;
#pragma unroll
    for (int h = 0; h < 4; h++) {
      float vs = 0.f, vd = 0.f;
#pragma unroll
      for (int ntl = 0; ntl < 4; ntl++) {
        int nt = h * 4 + ntl;
        vs = fmaf(acc[nt][r], as_f[nt], vs);
        vd = fmaf(acc[nt][r], ad_f[nt], vd);
      }
#pragma unroll
      for (int off = 8; off > 0; off >>= 1) {
        vs += __shfl_down(vs, off, 16);
        vd += __shfl_down(vd, off, 16);
      }
      if (li == 0) {
        a1s[node * 4 + h] = vs * LOG2E;
        a1d[node * 4 + h] = vd * LOG2E;
      }
    }
  }
}

// ---------------- CSR scan chain (unpadded rows) ----------------
__global__ void scan_local(const int* __restrict__ deg, int* __restrict__ excl,
                           int* __restrict__ bsum, int N) {
  __shared__ int s[256];
  int i = blockIdx.x * 256 + threadIdx.x;
  int v = (i < N) ? deg[i] + 1 : 0;  // +1 self-loop
  s[threadIdx.x] = v;
  __syncthreads();
  for (int off = 1; off < 256; off <<= 1) {
    int t = (threadIdx.x >= off) ? s[threadIdx.x - off] : 0;
    __syncthreads();
    s[threadIdx.x] += t;
    __syncthreads();
  }
  if (i < N) excl[i] = s[threadIdx.x] - v;
  if (threadIdx.x == 255) bsum[blockIdx.x] = s[255];
}

// scan_add2: every block re-scans bsum in LDS (nb <= 256), writes rowptr + self-loop
__global__ void scan_add2(const int* __restrict__ excl, const int* __restrict__ bsum,
                          int* __restrict__ rowptr, int* __restrict__ elist,
                          int N, int nb) {
  __shared__ int s[256];
  int v = (threadIdx.x < nb) ? bsum[threadIdx.x] : 0;
  s[threadIdx.x] = v;
  __syncthreads();
  for (int off = 1; off < 256; off <<= 1) {
    int t = (threadIdx.x >= off) ? s[threadIdx.x - off] : 0;
    __syncthreads();
    s[threadIdx.x] += t;
    __syncthreads();
  }
  __syncthreads();
  int base = (blockIdx.x > 0) ? s[blockIdx.x - 1] : 0;  // exclusive block offset
  int i = blockIdx.x * 256 + threadIdx.x;
  if (i < N) {
    int r = excl[i] + base;
    rowptr[i] = r;
    elist[r] = i;  // self-loop first
  }
  if (blockIdx.x == 0 && threadIdx.x == 0) rowptr[N] = s[nb - 1];  // total = ET
}

// ---------------- atomic-free scatter via precomputed rank ----------------
__global__ void scatter2(const int* __restrict__ src, const int* __restrict__ dst,
                         const int* __restrict__ rank, const int* __restrict__ rowptr,
                         int* __restrict__ elist, int E) {
  int e = blockIdx.x * 256 + threadIdx.x;
  if (e >= E) return;
  elist[rowptr[dst[e]] + 1 + rank[e]] = src[e];
}

// ---------------- agg1: TWO nodes per wave (half-wave = one full node, 32 lanes x
// 8 int8 channels). One VMEM inst fetches 2 edges' rows. Epilogue staged through
// LDS cbuf, then the proven R10 epilogue (4ch/lane, stride-41 w2s) per node. --------
__global__ __launch_bounds__(256) void agg1_fused(
    const int* __restrict__ rowptr, const int* __restrict__ elist,
    const unsigned char* __restrict__ h1q, const float* __restrict__ hscale,
    const float* __restrict__ a1s, const float* __restrict__ a1d,
    const float* __restrict__ b1, const float* __restrict__ W2,
    const float* __restrict__ as2, const float* __restrict__ ad2,
    __half* __restrict__ h2, float* __restrict__ a2s, float* __restrict__ a2d,
    int N) {
  __shared__ float w2s[64 * 41];   // lane-stride 41 -> conflict-free
  __shared__ float cbuf[8][256];   // normalized pre-bias outputs of this block's nodes
  const int t = threadIdx.x;
  for (int i = t; i < 2560; i += 256) {
    int ch = i / 10, jj = i - ch * 10;
    w2s[(ch >> 2) * 41 + (ch & 3) * 10 + jj] = W2[i];
  }

  const int wave = t >> 6, lane = t & 63;
  const int half = lane >> 5, l32 = lane & 31;
  const int slot = wave * 2 + half;        // node slot in block: 0..7
  const int n = blockIdx.x * 8 + slot;
  const bool act = n < N;
  const int row = act ? rowptr[n] : 0;
  const int deg = act ? rowptr[n + 1] - row : 0;
  const int* el = elist + row;
  const int hidx = l32 >> 3;               // head of this lane's 8 channels
  const float adh = act ? a1d[n * 4 + hidx] : 0.f;  // pre-scaled by log2e

  float den = 0.f, T = 0.f;
  float acc[8];
#pragma unroll
  for (int k = 0; k < 8; k++) acc[k] = 0.f;

  int j = 0;
  for (; j + 4 <= deg; j += 4) {
    int ss[4];
    float lv[4], sc[4];
    uint2 qv[4];
#pragma unroll
    for (int u = 0; u < 4; u++) ss[u] = el[j + u];
#pragma unroll
    for (int u = 0; u < 4; u++) {
      lv[u] = a1s[ss[u] * 4 + hidx];
      sc[u] = hscale[ss[u]];
      qv[u] = *(const uint2*)(h1q + (size_t)ss[u] * 256 + l32 * 8);
    }
#pragma unroll
    for (int u = 0; u < 4; u++) {
      float l = lv[u] + adh;
      float e = EXP2(fmaxf(l, NEG_SLOPE * l));
      den += e;
      float se = e * sc[u];
      T += se;
      unsigned int a = qv[u].x, b = qv[u].y;
      acc[0] = fmaf((float)(a & 0xffu), se, acc[0]);
      acc[1] = fmaf((float)((a >> 8) & 0xffu), se, acc[1]);
      acc[2] = fmaf((float)((a >> 16) & 0xffu), se, acc[2]);
      acc[3] = fmaf((float)(a >> 24), se, acc[3]);
      acc[4] = fmaf((float)(b & 0xffu), se, acc[4]);
      acc[5] = fmaf((float)((b >> 8) & 0xffu), se, acc[5]);
      acc[6] = fmaf((float)((b >> 16) & 0xffu), se, acc[6]);
      acc[7] = fmaf((float)(b >> 24), se, acc[7]);
    }
  }
  for (; j < deg; j++) {
    int s0 = el[j];
    float l0 = a1s[s0 * 4 + hidx] + adh;
    float sc0 = hscale[s0];
    uint2 q0 = *(const uint2*)(h1q + (size_t)s0 * 256 + l32 * 8);
    float e0 = EXP2(fmaxf(l0, NEG_SLOPE * l0));
    den += e0;
    float se = e0 * sc0;
    T += se;
    unsigned int a = q0.x, b = q0.y;
    acc[0] = fmaf((float)(a & 0xffu), se, acc[0]);
    acc[1] = fmaf((float)((a >> 8) & 0xffu), se, acc[1]);
    acc[2] = fmaf((float)((a >> 16) & 0xffu), se, acc[2]);
    acc[3] = fmaf((float)(a >> 24), se, acc[3]);
    acc[4] = fmaf((float)(b & 0xffu), se, acc[4]);
    acc[5] = fmaf((float)((b >> 8) & 0xffu), se, acc[5]);
    acc[6] = fmaf((float)((b >> 16) & 0xffu), se, acc[6]);
    acc[7] = fmaf((float)(b >> 24), se, acc[7]);
  }

  // normalized, offset-corrected, pre-bias values -> LDS
  if (act) {
    float inv = 1.0f / den;
    float corr = 128.0f * T;
    float4 v0 = make_float4((acc[0] - corr) * inv, (acc[1] - corr) * inv,
                            (acc[2] - corr) * inv, (acc[3] - corr) * inv);
    float4 v1 = make_float4((acc[4] - corr) * inv, (acc[5] - corr) * inv,
                            (acc[6] - corr) * inv, (acc[7] - corr) * inv);
    *(float4*)&cbuf[slot][l32 * 8] = v0;
    *(float4*)&cbuf[slot][l32 * 8 + 4] = v1;
  }
  __syncthreads();

  // epilogue (R10 layout): wave handles its 2 nodes sequentially, 4 ch/lane
  float4 bb = *(const float4*)(b1 + lane * 4);
  const float* w0 = w2s + lane * 41;
#pragma unroll
  for (int pp = 0; pp < 2; pp++) {
    int slot2 = wave * 2 + pp;
    int n2 = blockIdx.x * 8 + slot2;
    if (n2 >= N) continue;  // uniform per wave
    float4 cv = *(const float4*)&cbuf[slot2][lane * 4];
    float c0 = cv.x + bb.x;
    float c1 = cv.y + bb.y;
    float c2 = cv.z + bb.z;
    float c3 = cv.w + bb.w;
    c0 = c0 > 0.f ? c0 : expm1f(c0);
    c1 = c1 > 0.f ? c1 : expm1f(c1);
    c2 = c2 > 0.f ? c2 : expm1f(c2);
    c3 = c3 > 0.f ? c3 : expm1f(c3);
    float p[10];
#pragma unroll
    for (int jj = 0; jj < 10; jj++)
      p[jj] = fmaf(c0, w0[jj],
              fmaf(c1, w0[10 + jj], fmaf(c2, w0[20 + jj], c3 * w0[30 + jj])));
#pragma unroll
    for (int jj = 0; jj < 10; jj++) {
#pragma unroll
      for (int off = 32; off > 0; off >>= 1) p[jj] += __shfl_down(p[jj], off, 64);
    }
    if (lane == 0) {
      float ds = 0.f, dd = 0.f;
#pragma unroll
      for (int jj = 0; jj < 10; jj++) {
        h2[(size_t)n2 * 16 + jj] = __float2half(p[jj]);
        ds = fmaf(p[jj], as2[jj], ds);
        dd = fmaf(p[jj], ad2[jj], dd);
      }
      a2s[n2] = ds * LOG2E;
      a2d[n2] = dd * LOG2E;
    }
  }
}

// ---------------- agg2: wave-per-node, 12 groups x 5 lanes (half2 = 2 channels),
// unroll-2: 24 edge-slots per iteration, 5x less lane redundancy than R10 ----------
__global__ __launch_bounds__(256) void agg2_csr(
    const int* __restrict__ rowptr, const int* __restrict__ elist,
    const __half* __restrict__ h2, const float* __restrict__ a2s,
    const float* __restrict__ a2d, const float* __restrict__ b2,
    float* __restrict__ out, int N) {
  int wave = threadIdx.x >> 6, lane = threadIdx.x & 63;
  int n = blockIdx.x * 4 + wave;
  if (n >= N) return;
  int row = rowptr[n];
  int deg = rowptr[n + 1] - row;
  const int* el = elist + row;
  float ad = a2d[n];     // pre-scaled
  int g = lane / 5;      // 0..11 active, lanes 60-63 idle (g=12)
  int c2 = lane - g * 5; // channel-pair index 0..4
  float den = 0.f, ax = 0.f, ay = 0.f;
  if (g < 12) {
    int jj = g;
    for (; jj + 12 < deg; jj += 24) {
      int sA = el[jj], sB = el[jj + 12];
      float lA = a2s[sA] + ad;
      float lB = a2s[sB] + ad;
      __half2 hA = *(const __half2*)(h2 + (size_t)sA * 16 + c2 * 2);
      __half2 hB = *(const __half2*)(h2 + (size_t)sB * 16 + c2 * 2);
      float eA = EXP2(fmaxf(lA, NEG_SLOPE * lA));
      float eB = EXP2(fmaxf(lB, NEG_SLOPE * lB));
      den += eA + eB;
      float2 fA = __half22float2(hA);
      float2 fB = __half22float2(hB);
      ax = fmaf(eA, fA.x, fmaf(eB, fB.x, ax));
      ay = fmaf(eA, fA.y, fmaf(eB, fB.y, ay));
    }
    for (; jj < deg; jj += 12) {
      int s = el[jj];
      float l = a2s[s] + ad;
      __half2 hv = *(const __half2*)(h2 + (size_t)s * 16 + c2 * 2);
      float ev = EXP2(fmaxf(l, NEG_SLOPE * l));
      den += ev;
      float2 f = __half22float2(hv);
      ax = fmaf(ev, f.x, ax);
      ay = fmaf(ev, f.y, ay);
    }
  }
  // reduce the 12 stride-5 groups: +30 (g+6), then +10/+20 (g+2,g+4), then +5 (g+1)
  ax += __shfl_down(ax, 30, 64);
  ay += __shfl_down(ay, 30, 64);
  den += __shfl_down(den, 30, 64);
  ax += __shfl_down(ax, 10, 64) + __shfl_down(ax, 20, 64);
  ay += __shfl_down(ay, 10, 64) + __shfl_down(ay, 20, 64);
  den += __shfl_down(den, 10, 64) + __shfl_down(den, 20, 64);
  ax += __shfl_down(ax, 5, 64);
  ay += __shfl_down(ay, 5, 64);
  den += __shfl_down(den, 5, 64);
  if (lane < 5) {
    float inv = 1.0f / den;
    float2 bb = *(const float2*)(b2 + lane * 2);
    float2 o = make_float2(fmaf(ax, inv, bb.x), fmaf(ay, inv, bb.y));
    *(float2*)(out + (size_t)n * 10 + lane * 2) = o;
  }
}

extern "C" void kernel_launch(void* const* d_in, const int* in_sizes, int n_in,
                              void* d_out, int out_size, void* d_ws, size_t ws_size,
                              hipStream_t stream) {
  const float* x = (const float*)d_in[0];
  const int* ei = (const int*)d_in[1];
  const float* W1 = (const float*)d_in[2];
  const float* as1 = (const float*)d_in[3];
  const float* ad1 = (const float*)d_in[4];
  const float* b1 = (const float*)d_in[5];
  const float* W2 = (const float*)d_in[6];
  const float* as2 = (const float*)d_in[7];
  const float* ad2 = (const float*)d_in[8];
  const float* b2 = (const float*)d_in[9];
  float* out = (float*)d_out;

  const int N = in_sizes[0] / 128;   // 50000
  const int E = in_sizes[1] / 2;     // 800000
  const int* srcp = ei;
  const int* dstp = ei + E;

  char* ws = (char*)d_ws;
  size_t off = 0;
  auto alloc = [&](size_t nbytes) {
    char* p = ws + off;
    off += (nbytes + 255) & ~(size_t)255;
    return p;
  };
  unsigned char* h1q = (unsigned char*)alloc((size_t)N * 256);
  float* hscale = (float*)alloc((size_t)N * 4);
  half8* Bpack = (half8*)alloc((size_t)4096 * 16);
  float* a1s = (float*)alloc((size_t)N * 4 * 4);
  float* a1d = (float*)alloc((size_t)N * 4 * 4);
  __half* h2 = (__half*)alloc((size_t)N * 16 * 2);
  float* a2sv = (float*)alloc((size_t)N * 4);
  float* a2dv = (float*)alloc((size_t)N * 4);
  int* deg = (int*)alloc((size_t)N * 4);
  int* excl = (int*)alloc((size_t)N * 4);
  int* bsum = (int*)alloc(256 * 4);
  int* rowptr = (int*)alloc((size_t)(N + 1) * 4);
  int* rank = (int*)alloc((size_t)E * 4);
  int* elist = (int*)alloc((size_t)(E + (size_t)N) * 4);

  const int nb = (N + 255) / 256;          // 196
  const int gemmBlocks = (N / 16 + 3) / 4; // 782
  const int histBlocks = 512;

  // L1: pack W1 + zero deg
  prep1<<<16 + nb, 256, 0, stream>>>(W1, Bpack, deg, N);
  // L2: gemm1 (MFMA -> int8 + scales, fused att dots) || hist+rank
  phase2<<<gemmBlocks + histBlocks, 256, 0, stream>>>(
      x, Bpack, as1, ad1, h1q, hscale, a1s, a1d, dstp, deg, rank, N, E,
      gemmBlocks, histBlocks);
  // CSR: scan, rowptr + self-loops, atomic-free scatter
  scan_local<<<nb, 256, 0, stream>>>(deg, excl, bsum, N);
  scan_add2<<<nb, 256, 0, stream>>>(excl, bsum, rowptr, elist, N, nb);
  scatter2<<<(E + 255) / 256, 256, 0, stream>>>(srcp, dstp, rank, rowptr, elist, E);
  // layer 1 aggregate (+ fused GEMM2 / att2): 2 nodes per wave, 8 per block
  agg1_fused<<<(N + 7) / 8, 256, 0, stream>>>(rowptr, elist, h1q, hscale, a1s, a1d,
                                              b1, W2, as2, ad2, h2, a2sv, a2dv, N);
  // layer 2 aggregate
  agg2_csr<<<(N + 3) / 4, 256, 0, stream>>>(rowptr, elist, h2, a2sv, a2dv, b2, out, N);
}